// Round 1
// baseline (1439.696 us; speedup 1.0000x reference)
//
#include <hip/hip_runtime.h>
#include <hip/hip_bf16.h>

typedef __bf16 bf16_t;
typedef __bf16 bf16x8 __attribute__((ext_vector_type(8)));
typedef __bf16 bf16x4 __attribute__((ext_vector_type(4)));
typedef float f32x4 __attribute__((ext_vector_type(4)));

#define T_TOKENS 8192
#define DIM 1024
#define HID 2816
#define NE 8
#define H_ROWS 24576  // 16384 routed + 8192 shared

// ---- workspace layout (bytes) ----
static constexpr size_t H_OFF = 0;
static constexpr size_t H_BYTES = (size_t)H_ROWS * HID * 2;           // 138,412,032
static constexpr size_t CNT_OFF = H_OFF + H_BYTES;                    // int[8]
static constexpr size_t FILL_OFF = CNT_OFF + 32;                      // int[8]
static constexpr size_t OFFS_OFF = FILL_OFF + 32;                     // int[16]
static constexpr size_t TOPKI_OFF = OFFS_OFF + 64;                    // int[T][2]
static constexpr size_t TOPKW_OFF = TOPKI_OFF + (size_t)T_TOKENS * 2 * 4;
static constexpr size_t ROWMAP_OFF = TOPKW_OFF + (size_t)T_TOKENS * 2 * 4;
static constexpr size_t ROWW_OFF = ROWMAP_OFF + (size_t)H_ROWS * 4;

// ---------------- gating: one wave per token, fp64 dot to avoid top-k flips ----------------
__global__ void gate_kernel(const float* __restrict__ x, const float* __restrict__ gw,
                            int* __restrict__ topk_idx, float* __restrict__ topk_w,
                            int* __restrict__ counts)
{
    int tok = (blockIdx.x * blockDim.x + threadIdx.x) >> 6;
    int lane = threadIdx.x & 63;
    if (tok >= T_TOKENS) return;
    const float* xr = x + (size_t)tok * DIM;
    float xl[16];
#pragma unroll
    for (int i = 0; i < 16; i++) xl[i] = xr[lane + 64 * i];
    double lg[NE];
#pragma unroll
    for (int e = 0; e < NE; e++) {
        const float* g = gw + e * DIM;
        double s = 0.0;
#pragma unroll
        for (int i = 0; i < 16; i++) s += (double)xl[i] * (double)g[lane + 64 * i];
#pragma unroll
        for (int off = 32; off > 0; off >>= 1) s += __shfl_xor(s, off, 64);
        lg[e] = s;
    }
    if (lane == 0) {
        double mx = lg[0];
        for (int e = 1; e < NE; e++) mx = lg[e] > mx ? lg[e] : mx;
        double sum = 0.0, sc[NE];
        for (int e = 0; e < NE; e++) { sc[e] = exp(lg[e] - mx); sum += sc[e]; }
        for (int e = 0; e < NE; e++) sc[e] /= sum;
        int i0 = 0;
        for (int e = 1; e < NE; e++) if (sc[e] > sc[i0]) i0 = e;  // strict > : first occurrence wins (lax.top_k)
        int i1 = -1;
        for (int e = 0; e < NE; e++) { if (e == i0) continue; if (i1 < 0 || sc[e] > sc[i1]) i1 = e; }
        double s0 = sc[i0], s1 = sc[i1];
        double inv = 1.0 / (s0 + s1 + 1e-20);
        topk_idx[tok * 2 + 0] = i0;
        topk_idx[tok * 2 + 1] = i1;
        topk_w[tok * 2 + 0] = (float)(s0 * inv);
        topk_w[tok * 2 + 1] = (float)(s1 * inv);
        atomicAdd(&counts[i0], 1);
        atomicAdd(&counts[i1], 1);
    }
}

__global__ void offsets_kernel(const int* __restrict__ counts, int* __restrict__ offsets)
{
    if (threadIdx.x == 0) {
        int acc = 0;
        for (int e = 0; e < NE; e++) { offsets[e] = acc; acc += counts[e]; }
        offsets[8] = 16384;  // shared group base (acc == 16384 always)
        offsets[9] = H_ROWS;
    }
}

__global__ void scatter_kernel(const int* __restrict__ topk_idx, const float* __restrict__ topk_w,
                               const int* __restrict__ offsets, int* __restrict__ fill,
                               int* __restrict__ rowmap, float* __restrict__ roww)
{
    int t = blockIdx.x * blockDim.x + threadIdx.x;
    if (t >= T_TOKENS) return;
#pragma unroll
    for (int k = 0; k < 2; k++) {
        int e = topk_idx[t * 2 + k];
        int slot = atomicAdd(&fill[e], 1);
        int r = offsets[e] + slot;
        rowmap[r] = t;
        roww[r] = topk_w[t * 2 + k];
    }
    rowmap[16384 + t] = t;   // shared expert identity map
    roww[16384 + t] = 1.0f;
}

// ---------------- GEMM1: H[row, j] = silu(x.w1^T) * (x.w3^T), grouped by expert ----------------
// block 256 thr (4 waves), tile 128x128, BK=32, mfma 16x16x32 bf16
__global__ __launch_bounds__(256, 2)
void gemm1_kernel(const float* __restrict__ x,
                  const float* __restrict__ w1, const float* __restrict__ w3,
                  const float* __restrict__ sw1, const float* __restrict__ sw3,
                  const int* __restrict__ offsets, const int* __restrict__ counts,
                  const int* __restrict__ rowmap, bf16_t* __restrict__ Hout)
{
    const int g = blockIdx.y >> 6;        // 0..8 (8 = shared)
    const int mtile = blockIdx.y & 63;
    const int cnt = (g < NE) ? counts[g] : T_TOKENS;
    const int mbase = mtile * 128;
    if (mbase >= cnt) return;
    const int nbase = blockIdx.x * 128;   // HID/128 = 22 tiles
    const float* B1 = (g < NE) ? (w1 + (size_t)g * HID * DIM) : sw1;
    const float* B3 = (g < NE) ? (w3 + (size_t)g * HID * DIM) : sw3;
    const int rowoff = offsets[g];

    __shared__ bf16_t sA[128][40];   // +8 pad: 80B row stride, conflict-free b128
    __shared__ bf16_t sB1[128][40];
    __shared__ bf16_t sB3[128][40];

    const int tid = threadIdx.x;
    const int srow = tid >> 3;        // 0..31
    const int sk4 = (tid & 7) * 4;    // 0..28

    // token ids for the 4 A-rows this thread stages (unguarded: rowmap always valid memory)
    int tok[4];
#pragma unroll
    for (int i = 0; i < 4; i++) tok[i] = rowmap[rowoff + mbase + srow + 32 * i];

    const int wave = tid >> 6, lane = tid & 63;
    const int wm = (wave >> 1) * 64, wn = (wave & 1) * 64;
    const int fm = lane & 15, fq = lane >> 4;

    const f32x4 zero = {0.f, 0.f, 0.f, 0.f};
    f32x4 acc1[4][4], acc2[4][4];
#pragma unroll
    for (int i = 0; i < 4; i++)
#pragma unroll
        for (int j = 0; j < 4; j++) { acc1[i][j] = zero; acc2[i][j] = zero; }

    for (int k0 = 0; k0 < DIM; k0 += 32) {
#pragma unroll
        for (int i = 0; i < 4; i++) {
            const int r = srow + 32 * i;
            float4 va = *(const float4*)(x + (size_t)tok[i] * DIM + k0 + sk4);
            bf16x4 pa = {(bf16_t)va.x, (bf16_t)va.y, (bf16_t)va.z, (bf16_t)va.w};
            *(bf16x4*)&sA[r][sk4] = pa;
            float4 v1 = *(const float4*)(B1 + (size_t)(nbase + r) * DIM + k0 + sk4);
            bf16x4 p1 = {(bf16_t)v1.x, (bf16_t)v1.y, (bf16_t)v1.z, (bf16_t)v1.w};
            *(bf16x4*)&sB1[r][sk4] = p1;
            float4 v3 = *(const float4*)(B3 + (size_t)(nbase + r) * DIM + k0 + sk4);
            bf16x4 p3 = {(bf16_t)v3.x, (bf16_t)v3.y, (bf16_t)v3.z, (bf16_t)v3.w};
            *(bf16x4*)&sB3[r][sk4] = p3;
        }
        __syncthreads();
        bf16x8 af[4], bf1[4], bf3[4];
#pragma unroll
        for (int i = 0; i < 4; i++) {
            af[i]  = *(const bf16x8*)&sA[wm + i * 16 + fm][fq * 8];
            bf1[i] = *(const bf16x8*)&sB1[wn + i * 16 + fm][fq * 8];
            bf3[i] = *(const bf16x8*)&sB3[wn + i * 16 + fm][fq * 8];
        }
#pragma unroll
        for (int i = 0; i < 4; i++)
#pragma unroll
            for (int j = 0; j < 4; j++) {
                acc1[i][j] = __builtin_amdgcn_mfma_f32_16x16x32_bf16(af[i], bf1[j], acc1[i][j], 0, 0, 0);
                acc2[i][j] = __builtin_amdgcn_mfma_f32_16x16x32_bf16(af[i], bf3[j], acc2[i][j], 0, 0, 0);
            }
        __syncthreads();
    }

    // epilogue: h = silu(p1)*p2, bf16 store into packed H
    const size_t hbase = (size_t)(rowoff + mbase);
#pragma unroll
    for (int i = 0; i < 4; i++) {
#pragma unroll
        for (int r = 0; r < 4; r++) {
            const int lr = wm + i * 16 + fq * 4 + r;
            if (mbase + lr < cnt) {
                bf16_t* hp = Hout + (hbase + lr) * (size_t)HID + nbase + wn;
#pragma unroll
                for (int j = 0; j < 4; j++) {
                    float v1 = acc1[i][j][r];
                    float v2 = acc2[i][j][r];
                    float h = (v1 / (1.f + __expf(-v1))) * v2;
                    hp[j * 16 + fm] = (bf16_t)h;
                }
            }
        }
    }
}

// ---------------- GEMM2: out[t, d] (+)= w * (H . w2^T) ----------------
template <bool ATOMIC>
__global__ __launch_bounds__(256, 2)
void gemm2_kernel(const bf16_t* __restrict__ Hin,
                  const float* __restrict__ w2, const float* __restrict__ sw2,
                  const int* __restrict__ offsets, const int* __restrict__ counts,
                  const int* __restrict__ rowmap, const float* __restrict__ roww,
                  float* __restrict__ out, int gbase)
{
    const int g = gbase + (blockIdx.y >> 6);
    const int mtile = blockIdx.y & 63;
    const int cnt = (g < NE) ? counts[g] : T_TOKENS;
    const int mbase = mtile * 128;
    if (mbase >= cnt) return;
    const int nbase = blockIdx.x * 128;   // DIM/128 = 8 tiles
    const float* B = (g < NE) ? (w2 + (size_t)g * DIM * HID) : sw2;
    const int rowoff = offsets[g];

    __shared__ bf16_t sA[128][40];
    __shared__ bf16_t sB[128][40];

    const int tid = threadIdx.x;
    const int arow = tid >> 2;          // 0..63 (A: bf16, 16B loads)
    const int ak8 = (tid & 3) * 8;
    const int brow = tid >> 3;          // 0..31 (B: fp32 -> bf16)
    const int bk4 = (tid & 7) * 4;

    const int wave = tid >> 6, lane = tid & 63;
    const int wm = (wave >> 1) * 64, wn = (wave & 1) * 64;
    const int fm = lane & 15, fq = lane >> 4;

    const f32x4 zero = {0.f, 0.f, 0.f, 0.f};
    f32x4 acc[4][4];
#pragma unroll
    for (int i = 0; i < 4; i++)
#pragma unroll
        for (int j = 0; j < 4; j++) acc[i][j] = zero;

    const size_t habase = (size_t)(rowoff + mbase);

    for (int k0 = 0; k0 < HID; k0 += 32) {
#pragma unroll
        for (int i = 0; i < 2; i++) {
            const int r = arow + 64 * i;
            bf16x8 v = *(const bf16x8*)(Hin + (habase + r) * (size_t)HID + k0 + ak8);
            *(bf16x8*)&sA[r][ak8] = v;
        }
#pragma unroll
        for (int i = 0; i < 4; i++) {
            const int r = brow + 32 * i;
            float4 vb = *(const float4*)(B + (size_t)(nbase + r) * HID + k0 + bk4);
            bf16x4 pb = {(bf16_t)vb.x, (bf16_t)vb.y, (bf16_t)vb.z, (bf16_t)vb.w};
            *(bf16x4*)&sB[r][bk4] = pb;
        }
        __syncthreads();
        bf16x8 af[4], bbf[4];
#pragma unroll
        for (int i = 0; i < 4; i++) {
            af[i]  = *(const bf16x8*)&sA[wm + i * 16 + fm][fq * 8];
            bbf[i] = *(const bf16x8*)&sB[wn + i * 16 + fm][fq * 8];
        }
#pragma unroll
        for (int i = 0; i < 4; i++)
#pragma unroll
            for (int j = 0; j < 4; j++)
                acc[i][j] = __builtin_amdgcn_mfma_f32_16x16x32_bf16(af[i], bbf[j], acc[i][j], 0, 0, 0);
        __syncthreads();
    }

#pragma unroll
    for (int i = 0; i < 4; i++) {
#pragma unroll
        for (int r = 0; r < 4; r++) {
            const int lr = wm + i * 16 + fq * 4 + r;
            if (mbase + lr < cnt) {
                const int row = rowoff + mbase + lr;
                const int t = rowmap[row];
                const float wgt = roww[row];
                float* op = out + (size_t)t * DIM + nbase + wn;
#pragma unroll
                for (int j = 0; j < 4; j++) {
                    float v = acc[i][j][r] * wgt;
                    if (ATOMIC) atomicAdd(&op[j * 16 + fm], v);
                    else op[j * 16 + fm] = v;
                }
            }
        }
    }
}

extern "C" void kernel_launch(void* const* d_in, const int* in_sizes, int n_in,
                              void* d_out, int out_size, void* d_ws, size_t ws_size,
                              hipStream_t stream)
{
    const float* x   = (const float*)d_in[0];
    const float* gw  = (const float*)d_in[1];
    const float* w1  = (const float*)d_in[2];
    const float* w2  = (const float*)d_in[3];
    const float* w3  = (const float*)d_in[4];
    const float* sw1 = (const float*)d_in[5];
    const float* sw2 = (const float*)d_in[6];
    const float* sw3 = (const float*)d_in[7];
    float* out = (float*)d_out;
    char* ws = (char*)d_ws;

    bf16_t* H   = (bf16_t*)(ws + H_OFF);
    int* counts = (int*)(ws + CNT_OFF);
    int* fill   = (int*)(ws + FILL_OFF);
    int* offs   = (int*)(ws + OFFS_OFF);
    int* tki    = (int*)(ws + TOPKI_OFF);
    float* tkw  = (float*)(ws + TOPKW_OFF);
    int* rowmap = (int*)(ws + ROWMAP_OFF);
    float* roww = (float*)(ws + ROWW_OFF);

    (void)in_sizes; (void)n_in; (void)out_size; (void)ws_size;

    hipMemsetAsync(ws + CNT_OFF, 0, 64, stream);  // counts + fill
    gate_kernel<<<T_TOKENS / 4, 256, 0, stream>>>(x, gw, tki, tkw, counts);
    offsets_kernel<<<1, 64, 0, stream>>>(counts, offs);
    scatter_kernel<<<T_TOKENS / 256, 256, 0, stream>>>(tki, tkw, offs, fill, rowmap, roww);
    gemm1_kernel<<<dim3(HID / 128, 9 * 64), 256, 0, stream>>>(x, w1, w3, sw1, sw3, offs, counts, rowmap, H);
    // shared expert first: plain stores initialize every out element (no memset needed)
    gemm2_kernel<false><<<dim3(DIM / 128, 64), 256, 0, stream>>>(H, w2, sw2, offs, counts, rowmap, roww, out, 8);
    // routed experts: weighted atomic accumulate
    gemm2_kernel<true><<<dim3(DIM / 128, 8 * 64), 256, 0, stream>>>(H, w2, sw2, offs, counts, rowmap, roww, out, 0);
}

// Round 2
// 1164.475 us; speedup vs baseline: 1.2363x; 1.2363x over previous
//
#include <hip/hip_runtime.h>
#include <hip/hip_bf16.h>

typedef __bf16 bf16_t;
typedef __bf16 bf16x8 __attribute__((ext_vector_type(8)));
typedef __bf16 bf16x4 __attribute__((ext_vector_type(4)));
typedef float f32x4 __attribute__((ext_vector_type(4)));

#define T_TOKENS 8192
#define DIM 1024
#define HID 2816
#define NE 8
#define H_ROWS 24576  // 16384 routed + 8192 shared

// async global->LDS, 16B per lane; LDS dest = uniform base + lane*16
#define GLDS(gp, lp)                                                              \
    __builtin_amdgcn_global_load_lds(                                             \
        (const __attribute__((address_space(1))) void*)(const void*)(gp),         \
        (__attribute__((address_space(3))) void*)(void*)(lp), 16, 0, 0)

// ---- workspace layout (bytes) ----
static constexpr size_t H_OFF = 0;
static constexpr size_t H_BYTES = (size_t)H_ROWS * HID * 2;           // 138,412,032
static constexpr size_t CNT_OFF = H_OFF + H_BYTES;                    // int[8]
static constexpr size_t FILL_OFF = CNT_OFF + 32;                      // int[8]
static constexpr size_t OFFS_OFF = FILL_OFF + 32;                     // int[16]
static constexpr size_t TOPKI_OFF = OFFS_OFF + 64;                    // int[T][2]
static constexpr size_t TOPKW_OFF = TOPKI_OFF + (size_t)T_TOKENS * 2 * 4;
static constexpr size_t ROWMAP_OFF = TOPKW_OFF + (size_t)T_TOKENS * 2 * 4;
static constexpr size_t ROWW_OFF = ROWMAP_OFF + (size_t)H_ROWS * 4;
static constexpr size_t XB_OFF = (ROWW_OFF + (size_t)H_ROWS * 4 + 255) & ~(size_t)255;
static constexpr size_t XB_BYTES = (size_t)T_TOKENS * DIM * 2;        // 16.8 MB
static constexpr size_t W1B_OFF = XB_OFF + XB_BYTES;                  // 9 experts (8 routed + shared)
static constexpr size_t WEB_BYTES = (size_t)9 * HID * DIM * 2;        // 51.9 MB
static constexpr size_t W3B_OFF = W1B_OFF + WEB_BYTES;
static constexpr size_t W2B_OFF = W3B_OFF + WEB_BYTES;

// ---------------- fp32 -> bf16 conversion of x + all weights ----------------
struct CvtArgs {
    const float* s[7];
    bf16_t* d[7];
    int n4[7];
};

__global__ void convert_kernel(CvtArgs a)
{
    const int t = blockIdx.y;
    const float4* s = (const float4*)a.s[t];
    bf16x4* d = (bf16x4*)a.d[t];
    const int n4 = a.n4[t];
    for (int i = blockIdx.x * blockDim.x + threadIdx.x; i < n4; i += gridDim.x * blockDim.x) {
        float4 v = s[i];
        bf16x4 b = {(bf16_t)v.x, (bf16_t)v.y, (bf16_t)v.z, (bf16_t)v.w};
        d[i] = b;
    }
}

// ---------------- gating: one wave per token, fp64 dot to avoid top-k flips ----------------
__global__ void gate_kernel(const float* __restrict__ x, const float* __restrict__ gw,
                            int* __restrict__ topk_idx, float* __restrict__ topk_w,
                            int* __restrict__ counts)
{
    int tok = (blockIdx.x * blockDim.x + threadIdx.x) >> 6;
    int lane = threadIdx.x & 63;
    if (tok >= T_TOKENS) return;
    const float* xr = x + (size_t)tok * DIM;
    float xl[16];
#pragma unroll
    for (int i = 0; i < 16; i++) xl[i] = xr[lane + 64 * i];
    double lg[NE];
#pragma unroll
    for (int e = 0; e < NE; e++) {
        const float* g = gw + e * DIM;
        double s = 0.0;
#pragma unroll
        for (int i = 0; i < 16; i++) s += (double)xl[i] * (double)g[lane + 64 * i];
#pragma unroll
        for (int off = 32; off > 0; off >>= 1) s += __shfl_xor(s, off, 64);
        lg[e] = s;
    }
    if (lane == 0) {
        double mx = lg[0];
        for (int e = 1; e < NE; e++) mx = lg[e] > mx ? lg[e] : mx;
        double sum = 0.0, sc[NE];
        for (int e = 0; e < NE; e++) { sc[e] = exp(lg[e] - mx); sum += sc[e]; }
        for (int e = 0; e < NE; e++) sc[e] /= sum;
        int i0 = 0;
        for (int e = 1; e < NE; e++) if (sc[e] > sc[i0]) i0 = e;  // strict > : first occurrence wins
        int i1 = -1;
        for (int e = 0; e < NE; e++) { if (e == i0) continue; if (i1 < 0 || sc[e] > sc[i1]) i1 = e; }
        double s0 = sc[i0], s1 = sc[i1];
        double inv = 1.0 / (s0 + s1 + 1e-20);
        topk_idx[tok * 2 + 0] = i0;
        topk_idx[tok * 2 + 1] = i1;
        topk_w[tok * 2 + 0] = (float)(s0 * inv);
        topk_w[tok * 2 + 1] = (float)(s1 * inv);
        atomicAdd(&counts[i0], 1);
        atomicAdd(&counts[i1], 1);
    }
}

__global__ void offsets_kernel(const int* __restrict__ counts, int* __restrict__ offsets)
{
    if (threadIdx.x == 0) {
        int acc = 0;
        for (int e = 0; e < NE; e++) { offsets[e] = acc; acc += counts[e]; }
        offsets[8] = 16384;  // shared group base
        offsets[9] = H_ROWS;
    }
}

__global__ void scatter_kernel(const int* __restrict__ topk_idx, const float* __restrict__ topk_w,
                               const int* __restrict__ offsets, int* __restrict__ fill,
                               int* __restrict__ rowmap, float* __restrict__ roww)
{
    int t = blockIdx.x * blockDim.x + threadIdx.x;
    if (t >= T_TOKENS) return;
#pragma unroll
    for (int k = 0; k < 2; k++) {
        int e = topk_idx[t * 2 + k];
        int slot = atomicAdd(&fill[e], 1);
        int r = offsets[e] + slot;
        rowmap[r] = t;
        roww[r] = topk_w[t * 2 + k];
    }
    rowmap[16384 + t] = t;   // shared expert identity map
    roww[16384 + t] = 1.0f;
}

// ---------------- GEMM1: H = silu(x.w1^T) * (x.w3^T), grouped, glds staging ----------------
// block 256 (4 waves), tile 128x128, BK=64, mfma 16x16x32 bf16
// LDS layout: 16B units, data (row, c) stored at unit row*8 + (c ^ ((row>>1)&7))
__global__ __launch_bounds__(256, 2)
void gemm1_kernel(const bf16_t* __restrict__ xb,
                  const bf16_t* __restrict__ w1b, const bf16_t* __restrict__ w3b,
                  const int* __restrict__ offsets, const int* __restrict__ counts,
                  const int* __restrict__ rowmap, bf16_t* __restrict__ Hout)
{
    const int g = blockIdx.y >> 6;        // 0..8 (8 = shared)
    const int mtile = blockIdx.y & 63;
    const int cnt = (g < NE) ? counts[g] : T_TOKENS;
    const int mbase = mtile * 128;
    if (mbase >= cnt) return;
    const int nbase = blockIdx.x * 128;   // HID/128 = 22
    const int rowoff = offsets[g];
    const bf16_t* B1 = w1b + (size_t)g * HID * DIM;
    const bf16_t* B3 = w3b + (size_t)g * HID * DIM;

    __shared__ bf16_t sA[128 * 64];
    __shared__ bf16_t sB1[128 * 64];
    __shared__ bf16_t sB3[128 * 64];

    const int tid = threadIdx.x;
    const int wave = tid >> 6, lane = tid & 63;

    // staging source pointers: unit U = wave*256 + t*64 + lane
    const bf16_t* pa[4]; const bf16_t* pb1[4]; const bf16_t* pb3[4];
#pragma unroll
    for (int t = 0; t < 4; t++) {
        const int U = wave * 256 + t * 64 + lane;
        const int row = U >> 3;
        const int c = (U & 7) ^ ((row >> 1) & 7);   // swizzled data col (16B units)
        const int tok = rowmap[rowoff + mbase + row];
        pa[t]  = xb + (size_t)tok * DIM + c * 8;
        pb1[t] = B1 + (size_t)(nbase + row) * DIM + c * 8;
        pb3[t] = B3 + (size_t)(nbase + row) * DIM + c * 8;
    }

    const int wm = (wave >> 1) * 64, wn = (wave & 1) * 64;
    const int fm = lane & 15, fq = lane >> 4;
    const int swz = (fm >> 1) & 7;
    int aoff[4][2], boff[4][2];   // LDS elem offsets per (sub-tile, ksub)
#pragma unroll
    for (int i = 0; i < 4; i++)
#pragma unroll
        for (int s = 0; s < 2; s++) {
            aoff[i][s] = (wm + i * 16 + fm) * 64 + ((s * 4 + fq) ^ swz) * 8;
            boff[i][s] = (wn + i * 16 + fm) * 64 + ((s * 4 + fq) ^ swz) * 8;
        }

    const f32x4 zero = {0.f, 0.f, 0.f, 0.f};
    f32x4 acc1[4][4], acc2[4][4];
#pragma unroll
    for (int i = 0; i < 4; i++)
#pragma unroll
        for (int j = 0; j < 4; j++) { acc1[i][j] = zero; acc2[i][j] = zero; }

    for (int k0 = 0; k0 < DIM; k0 += 64) {
#pragma unroll
        for (int t = 0; t < 4; t++) {
            const int lb = (wave * 256 + t * 64) * 8;
            GLDS(pa[t],  &sA[lb]);
            GLDS(pb1[t], &sB1[lb]);
            GLDS(pb3[t], &sB3[lb]);
            pa[t] += 64; pb1[t] += 64; pb3[t] += 64;
        }
        __syncthreads();
#pragma unroll
        for (int s = 0; s < 2; s++) {
            bf16x8 af[4], b1f[4], b3f[4];
#pragma unroll
            for (int i = 0; i < 4; i++) {
                af[i]  = *(const bf16x8*)&sA[aoff[i][s]];
                b1f[i] = *(const bf16x8*)&sB1[boff[i][s]];
                b3f[i] = *(const bf16x8*)&sB3[boff[i][s]];
            }
#pragma unroll
            for (int i = 0; i < 4; i++)
#pragma unroll
                for (int j = 0; j < 4; j++) {
                    acc1[i][j] = __builtin_amdgcn_mfma_f32_16x16x32_bf16(af[i], b1f[j], acc1[i][j], 0, 0, 0);
                    acc2[i][j] = __builtin_amdgcn_mfma_f32_16x16x32_bf16(af[i], b3f[j], acc2[i][j], 0, 0, 0);
                }
        }
        __syncthreads();
    }

    // epilogue: h = silu(p1)*p2, bf16 store into packed H
    const size_t hbase = (size_t)(rowoff + mbase);
#pragma unroll
    for (int i = 0; i < 4; i++) {
#pragma unroll
        for (int r = 0; r < 4; r++) {
            const int lr = wm + i * 16 + fq * 4 + r;
            if (mbase + lr < cnt) {
                bf16_t* hp = Hout + (hbase + lr) * (size_t)HID + nbase + wn;
#pragma unroll
                for (int j = 0; j < 4; j++) {
                    float v1 = acc1[i][j][r];
                    float v2 = acc2[i][j][r];
                    float h = (v1 / (1.f + __expf(-v1))) * v2;
                    hp[j * 16 + fm] = (bf16_t)h;
                }
            }
        }
    }
}

// ---------------- GEMM2: out[t, d] (+)= w * (H . w2^T), glds staging ----------------
template <bool ATOMIC>
__global__ __launch_bounds__(256, 3)
void gemm2_kernel(const bf16_t* __restrict__ Hin, const bf16_t* __restrict__ w2b,
                  const int* __restrict__ offsets, const int* __restrict__ counts,
                  const int* __restrict__ rowmap, const float* __restrict__ roww,
                  float* __restrict__ out, int gbase)
{
    const int g = gbase + (blockIdx.y >> 6);
    const int mtile = blockIdx.y & 63;
    const int cnt = (g < NE) ? counts[g] : T_TOKENS;
    const int mbase = mtile * 128;
    if (mbase >= cnt) return;
    const int nbase = blockIdx.x * 128;   // DIM/128 = 8
    const int rowoff = offsets[g];
    const bf16_t* B = w2b + (size_t)g * DIM * HID;
    const size_t habase = (size_t)(rowoff + mbase);

    __shared__ bf16_t sA[128 * 64];
    __shared__ bf16_t sB[128 * 64];

    const int tid = threadIdx.x;
    const int wave = tid >> 6, lane = tid & 63;

    const bf16_t* pa[4]; const bf16_t* pb[4];
#pragma unroll
    for (int t = 0; t < 4; t++) {
        const int U = wave * 256 + t * 64 + lane;
        const int row = U >> 3;
        const int c = (U & 7) ^ ((row >> 1) & 7);
        pa[t] = Hin + (habase + row) * (size_t)HID + c * 8;
        pb[t] = B + (size_t)(nbase + row) * HID + c * 8;
    }

    const int wm = (wave >> 1) * 64, wn = (wave & 1) * 64;
    const int fm = lane & 15, fq = lane >> 4;
    const int swz = (fm >> 1) & 7;
    int aoff[4][2], boff[4][2];
#pragma unroll
    for (int i = 0; i < 4; i++)
#pragma unroll
        for (int s = 0; s < 2; s++) {
            aoff[i][s] = (wm + i * 16 + fm) * 64 + ((s * 4 + fq) ^ swz) * 8;
            boff[i][s] = (wn + i * 16 + fm) * 64 + ((s * 4 + fq) ^ swz) * 8;
        }

    const f32x4 zero = {0.f, 0.f, 0.f, 0.f};
    f32x4 acc[4][4];
#pragma unroll
    for (int i = 0; i < 4; i++)
#pragma unroll
        for (int j = 0; j < 4; j++) acc[i][j] = zero;

    for (int k0 = 0; k0 < HID; k0 += 64) {
#pragma unroll
        for (int t = 0; t < 4; t++) {
            const int lb = (wave * 256 + t * 64) * 8;
            GLDS(pa[t], &sA[lb]);
            GLDS(pb[t], &sB[lb]);
            pa[t] += 64; pb[t] += 64;
        }
        __syncthreads();
#pragma unroll
        for (int s = 0; s < 2; s++) {
            bf16x8 af[4], bbf[4];
#pragma unroll
            for (int i = 0; i < 4; i++) {
                af[i]  = *(const bf16x8*)&sA[aoff[i][s]];
                bbf[i] = *(const bf16x8*)&sB[boff[i][s]];
            }
#pragma unroll
            for (int i = 0; i < 4; i++)
#pragma unroll
                for (int j = 0; j < 4; j++)
                    acc[i][j] = __builtin_amdgcn_mfma_f32_16x16x32_bf16(af[i], bbf[j], acc[i][j], 0, 0, 0);
        }
        __syncthreads();
    }

#pragma unroll
    for (int i = 0; i < 4; i++) {
#pragma unroll
        for (int r = 0; r < 4; r++) {
            const int lr = wm + i * 16 + fq * 4 + r;
            if (mbase + lr < cnt) {
                const int row = rowoff + mbase + lr;
                const int t = rowmap[row];
                const float wgt = roww[row];
                float* op = out + (size_t)t * DIM + nbase + wn;
#pragma unroll
                for (int j = 0; j < 4; j++) {
                    float v = acc[i][j][r] * wgt;
                    if (ATOMIC) atomicAdd(&op[j * 16 + fm], v);
                    else op[j * 16 + fm] = v;
                }
            }
        }
    }
}

extern "C" void kernel_launch(void* const* d_in, const int* in_sizes, int n_in,
                              void* d_out, int out_size, void* d_ws, size_t ws_size,
                              hipStream_t stream)
{
    const float* x   = (const float*)d_in[0];
    const float* gw  = (const float*)d_in[1];
    const float* w1  = (const float*)d_in[2];
    const float* w2  = (const float*)d_in[3];
    const float* w3  = (const float*)d_in[4];
    const float* sw1 = (const float*)d_in[5];
    const float* sw2 = (const float*)d_in[6];
    const float* sw3 = (const float*)d_in[7];
    float* out = (float*)d_out;
    char* ws = (char*)d_ws;

    bf16_t* H   = (bf16_t*)(ws + H_OFF);
    int* counts = (int*)(ws + CNT_OFF);
    int* fill   = (int*)(ws + FILL_OFF);
    int* offs   = (int*)(ws + OFFS_OFF);
    int* tki    = (int*)(ws + TOPKI_OFF);
    float* tkw  = (float*)(ws + TOPKW_OFF);
    int* rowmap = (int*)(ws + ROWMAP_OFF);
    float* roww = (float*)(ws + ROWW_OFF);
    bf16_t* xb  = (bf16_t*)(ws + XB_OFF);
    bf16_t* w1b = (bf16_t*)(ws + W1B_OFF);
    bf16_t* w3b = (bf16_t*)(ws + W3B_OFF);
    bf16_t* w2b = (bf16_t*)(ws + W2B_OFF);

    (void)in_sizes; (void)n_in; (void)out_size; (void)ws_size;

    hipMemsetAsync(ws + CNT_OFF, 0, 64, stream);  // counts + fill

    CvtArgs ca;
    ca.s[0] = x;   ca.d[0] = xb;                        ca.n4[0] = T_TOKENS * DIM / 4;
    ca.s[1] = w1;  ca.d[1] = w1b;                       ca.n4[1] = NE * HID * DIM / 4;
    ca.s[2] = sw1; ca.d[2] = w1b + (size_t)NE * HID * DIM; ca.n4[2] = HID * DIM / 4;
    ca.s[3] = w3;  ca.d[3] = w3b;                       ca.n4[3] = NE * HID * DIM / 4;
    ca.s[4] = sw3; ca.d[4] = w3b + (size_t)NE * HID * DIM; ca.n4[4] = HID * DIM / 4;
    ca.s[5] = w2;  ca.d[5] = w2b;                       ca.n4[5] = NE * DIM * HID / 4;
    ca.s[6] = sw2; ca.d[6] = w2b + (size_t)NE * DIM * HID; ca.n4[6] = DIM * HID / 4;
    convert_kernel<<<dim3(1024, 7), 256, 0, stream>>>(ca);

    gate_kernel<<<T_TOKENS / 4, 256, 0, stream>>>(x, gw, tki, tkw, counts);
    offsets_kernel<<<1, 64, 0, stream>>>(counts, offs);
    scatter_kernel<<<T_TOKENS / 256, 256, 0, stream>>>(tki, tkw, offs, fill, rowmap, roww);
    gemm1_kernel<<<dim3(HID / 128, 9 * 64), 256, 0, stream>>>(xb, w1b, w3b, offs, counts, rowmap, H);
    // shared expert first: plain stores initialize every out element
    gemm2_kernel<false><<<dim3(DIM / 128, 64), 256, 0, stream>>>(H, w2b, offs, counts, rowmap, roww, out, 8);
    // routed experts: weighted atomic accumulate
    gemm2_kernel<true><<<dim3(DIM / 128, 8 * 64), 256, 0, stream>>>(H, w2b, offs, counts, rowmap, roww, out, 0);
}

// Round 3
// 1154.563 us; speedup vs baseline: 1.2470x; 1.0086x over previous
//
#include <hip/hip_runtime.h>
#include <hip/hip_bf16.h>

typedef __bf16 bf16_t;
typedef __bf16 bf16x8 __attribute__((ext_vector_type(8)));
typedef __bf16 bf16x4 __attribute__((ext_vector_type(4)));
typedef float f32x4 __attribute__((ext_vector_type(4)));

#define T_TOKENS 8192
#define DIM 1024
#define HID 2816
#define NE 8
#define H_ROWS 24576  // 16384 routed + 8192 shared

// async global->LDS, 16B per lane; LDS dest = uniform base + lane*16
#define GLDS(gp, lp)                                                              \
    __builtin_amdgcn_global_load_lds(                                             \
        (const __attribute__((address_space(1))) void*)(const void*)(gp),         \
        (__attribute__((address_space(3))) void*)(void*)(lp), 16, 0, 0)

// ---- workspace layout (bytes) ----
static constexpr size_t H_OFF = 0;
static constexpr size_t H_BYTES = (size_t)H_ROWS * HID * 2;           // 138,412,032
static constexpr size_t CNT_OFF = H_OFF + H_BYTES;                    // int[8]
static constexpr size_t FILL_OFF = CNT_OFF + 32;                      // int[8]
static constexpr size_t OFFS_OFF = FILL_OFF + 32;                     // int[16]
static constexpr size_t TOPKI_OFF = OFFS_OFF + 64;                    // int[T][2]
static constexpr size_t TOPKW_OFF = TOPKI_OFF + (size_t)T_TOKENS * 2 * 4;
static constexpr size_t ROWMAP_OFF = TOPKW_OFF + (size_t)T_TOKENS * 2 * 4;
static constexpr size_t TOKROW_OFF = ROWMAP_OFF + (size_t)H_ROWS * 4; // int[T][2]
static constexpr size_t XB_OFF = (TOKROW_OFF + (size_t)T_TOKENS * 2 * 4 + 255) & ~(size_t)255;
static constexpr size_t XB_BYTES = (size_t)T_TOKENS * DIM * 2;        // 16.8 MB
static constexpr size_t W1B_OFF = XB_OFF + XB_BYTES;                  // 9 experts (8 routed + shared)
static constexpr size_t WEB_BYTES = (size_t)9 * HID * DIM * 2;        // 51.9 MB
static constexpr size_t W3B_OFF = W1B_OFF + WEB_BYTES;
static constexpr size_t W2B_OFF = W3B_OFF + WEB_BYTES;
// Y (fp32 partial outputs, 24576 x 1024 = 100.7 MB) overlays w1b/w3b: those are
// dead after gemm1 completes, and gemm2 (the Y writer) is ordered after gemm1.
static constexpr size_t Y_OFF = W1B_OFF;

// ---------------- fp32 -> bf16 conversion of x + all weights ----------------
struct CvtArgs {
    const float* s[7];
    bf16_t* d[7];
    int n8[7];
};

__global__ void convert_kernel(CvtArgs a)
{
    const int t = blockIdx.y;
    const float4* s = (const float4*)a.s[t];
    bf16x8* d = (bf16x8*)a.d[t];
    const int n8 = a.n8[t];
    for (int i = blockIdx.x * blockDim.x + threadIdx.x; i < n8; i += gridDim.x * blockDim.x) {
        float4 v0 = s[i * 2];
        float4 v1 = s[i * 2 + 1];
        bf16x8 b = {(bf16_t)v0.x, (bf16_t)v0.y, (bf16_t)v0.z, (bf16_t)v0.w,
                    (bf16_t)v1.x, (bf16_t)v1.y, (bf16_t)v1.z, (bf16_t)v1.w};
        d[i] = b;
    }
}

// ---------------- gating: one wave per token, fp64 dot to avoid top-k flips ----------------
__global__ void gate_kernel(const float* __restrict__ x, const float* __restrict__ gw,
                            int* __restrict__ topk_idx, float* __restrict__ topk_w,
                            int* __restrict__ counts)
{
    int tok = (blockIdx.x * blockDim.x + threadIdx.x) >> 6;
    int lane = threadIdx.x & 63;
    if (tok >= T_TOKENS) return;
    const float* xr = x + (size_t)tok * DIM;
    float xl[16];
#pragma unroll
    for (int i = 0; i < 16; i++) xl[i] = xr[lane + 64 * i];
    double lg[NE];
#pragma unroll
    for (int e = 0; e < NE; e++) {
        const float* g = gw + e * DIM;
        double s = 0.0;
#pragma unroll
        for (int i = 0; i < 16; i++) s += (double)xl[i] * (double)g[lane + 64 * i];
#pragma unroll
        for (int off = 32; off > 0; off >>= 1) s += __shfl_xor(s, off, 64);
        lg[e] = s;
    }
    if (lane == 0) {
        double mx = lg[0];
        for (int e = 1; e < NE; e++) mx = lg[e] > mx ? lg[e] : mx;
        double sum = 0.0, sc[NE];
        for (int e = 0; e < NE; e++) { sc[e] = exp(lg[e] - mx); sum += sc[e]; }
        for (int e = 0; e < NE; e++) sc[e] /= sum;
        int i0 = 0;
        for (int e = 1; e < NE; e++) if (sc[e] > sc[i0]) i0 = e;  // strict > : first occurrence wins
        int i1 = -1;
        for (int e = 0; e < NE; e++) { if (e == i0) continue; if (i1 < 0 || sc[e] > sc[i1]) i1 = e; }
        double s0 = sc[i0], s1 = sc[i1];
        double inv = 1.0 / (s0 + s1 + 1e-20);
        topk_idx[tok * 2 + 0] = i0;
        topk_idx[tok * 2 + 1] = i1;
        topk_w[tok * 2 + 0] = (float)(s0 * inv);
        topk_w[tok * 2 + 1] = (float)(s1 * inv);
        atomicAdd(&counts[i0], 1);
        atomicAdd(&counts[i1], 1);
    }
}

__global__ void offsets_kernel(const int* __restrict__ counts, int* __restrict__ offsets)
{
    if (threadIdx.x == 0) {
        int acc = 0;
        for (int e = 0; e < NE; e++) { offsets[e] = acc; acc += counts[e]; }
        offsets[8] = 16384;  // shared group base
        offsets[9] = H_ROWS;
    }
}

__global__ void scatter_kernel(const int* __restrict__ topk_idx,
                               const int* __restrict__ offsets, int* __restrict__ fill,
                               int* __restrict__ rowmap, int* __restrict__ tokrow)
{
    int t = blockIdx.x * blockDim.x + threadIdx.x;
    if (t >= T_TOKENS) return;
#pragma unroll
    for (int k = 0; k < 2; k++) {
        int e = topk_idx[t * 2 + k];
        int slot = atomicAdd(&fill[e], 1);
        int r = offsets[e] + slot;
        rowmap[r] = t;
        tokrow[t * 2 + k] = r;
    }
    rowmap[16384 + t] = t;   // shared expert identity map
}

// ---------------- GEMM1: H = silu(x.w1^T) * (x.w3^T), grouped, glds staging ----------------
// block 256 (4 waves), tile 128x128, BK=64, mfma 16x16x32 bf16
// LDS layout: 16B units, data (row, c) stored at unit row*8 + (c ^ ((row>>1)&7))
__global__ __launch_bounds__(256, 2)
void gemm1_kernel(const bf16_t* __restrict__ xb,
                  const bf16_t* __restrict__ w1b, const bf16_t* __restrict__ w3b,
                  const int* __restrict__ offsets, const int* __restrict__ counts,
                  const int* __restrict__ rowmap, bf16_t* __restrict__ Hout)
{
    const int g = blockIdx.y >> 6;        // 0..8 (8 = shared)
    const int mtile = blockIdx.y & 63;
    const int cnt = (g < NE) ? counts[g] : T_TOKENS;
    const int mbase = mtile * 128;
    if (mbase >= cnt) return;
    const int nbase = blockIdx.x * 128;   // HID/128 = 22
    const int rowoff = offsets[g];
    const bf16_t* B1 = w1b + (size_t)g * HID * DIM;
    const bf16_t* B3 = w3b + (size_t)g * HID * DIM;

    __shared__ bf16_t sA[128 * 64];
    __shared__ bf16_t sB1[128 * 64];
    __shared__ bf16_t sB3[128 * 64];

    const int tid = threadIdx.x;
    const int wave = tid >> 6, lane = tid & 63;

    // staging source pointers: unit U = wave*256 + t*64 + lane
    const bf16_t* pa[4]; const bf16_t* pb1[4]; const bf16_t* pb3[4];
#pragma unroll
    for (int t = 0; t < 4; t++) {
        const int U = wave * 256 + t * 64 + lane;
        const int row = U >> 3;
        const int c = (U & 7) ^ ((row >> 1) & 7);   // swizzled data col (16B units)
        const int tok = rowmap[rowoff + mbase + row];
        pa[t]  = xb + (size_t)tok * DIM + c * 8;
        pb1[t] = B1 + (size_t)(nbase + row) * DIM + c * 8;
        pb3[t] = B3 + (size_t)(nbase + row) * DIM + c * 8;
    }

    const int wm = (wave >> 1) * 64, wn = (wave & 1) * 64;
    const int fm = lane & 15, fq = lane >> 4;
    const int swz = (fm >> 1) & 7;
    int aoff[4][2], boff[4][2];   // LDS elem offsets per (sub-tile, ksub)
#pragma unroll
    for (int i = 0; i < 4; i++)
#pragma unroll
        for (int s = 0; s < 2; s++) {
            aoff[i][s] = (wm + i * 16 + fm) * 64 + ((s * 4 + fq) ^ swz) * 8;
            boff[i][s] = (wn + i * 16 + fm) * 64 + ((s * 4 + fq) ^ swz) * 8;
        }

    const f32x4 zero = {0.f, 0.f, 0.f, 0.f};
    f32x4 acc1[4][4], acc2[4][4];
#pragma unroll
    for (int i = 0; i < 4; i++)
#pragma unroll
        for (int j = 0; j < 4; j++) { acc1[i][j] = zero; acc2[i][j] = zero; }

    for (int k0 = 0; k0 < DIM; k0 += 64) {
#pragma unroll
        for (int t = 0; t < 4; t++) {
            const int lb = (wave * 256 + t * 64) * 8;
            GLDS(pa[t],  &sA[lb]);
            GLDS(pb1[t], &sB1[lb]);
            GLDS(pb3[t], &sB3[lb]);
            pa[t] += 64; pb1[t] += 64; pb3[t] += 64;
        }
        __syncthreads();
#pragma unroll
        for (int s = 0; s < 2; s++) {
            bf16x8 af[4], b1f[4], b3f[4];
#pragma unroll
            for (int i = 0; i < 4; i++) {
                af[i]  = *(const bf16x8*)&sA[aoff[i][s]];
                b1f[i] = *(const bf16x8*)&sB1[boff[i][s]];
                b3f[i] = *(const bf16x8*)&sB3[boff[i][s]];
            }
#pragma unroll
            for (int i = 0; i < 4; i++)
#pragma unroll
                for (int j = 0; j < 4; j++) {
                    acc1[i][j] = __builtin_amdgcn_mfma_f32_16x16x32_bf16(af[i], b1f[j], acc1[i][j], 0, 0, 0);
                    acc2[i][j] = __builtin_amdgcn_mfma_f32_16x16x32_bf16(af[i], b3f[j], acc2[i][j], 0, 0, 0);
                }
        }
        __syncthreads();
    }

    // epilogue: h = silu(p1)*p2, bf16 store into packed H
    const size_t hbase = (size_t)(rowoff + mbase);
#pragma unroll
    for (int i = 0; i < 4; i++) {
#pragma unroll
        for (int r = 0; r < 4; r++) {
            const int lr = wm + i * 16 + fq * 4 + r;
            if (mbase + lr < cnt) {
                bf16_t* hp = Hout + (hbase + lr) * (size_t)HID + nbase + wn;
#pragma unroll
                for (int j = 0; j < 4; j++) {
                    float v1 = acc1[i][j][r];
                    float v2 = acc2[i][j][r];
                    float h = (v1 / (1.f + __expf(-v1))) * v2;
                    hp[j * 16 + fm] = (bf16_t)h;
                }
            }
        }
    }
}

// ---------------- GEMM2: Y[row, d] = H[row] . w2[g]^T  (unweighted partials) ----------------
__global__ __launch_bounds__(256, 3)
void gemm2_kernel(const bf16_t* __restrict__ Hin, const bf16_t* __restrict__ w2b,
                  const int* __restrict__ offsets, const int* __restrict__ counts,
                  float* __restrict__ Y)
{
    const int g = blockIdx.y >> 6;        // 0..8
    const int mtile = blockIdx.y & 63;
    const int cnt = (g < NE) ? counts[g] : T_TOKENS;
    const int mbase = mtile * 128;
    if (mbase >= cnt) return;
    const int nbase = blockIdx.x * 128;   // DIM/128 = 8
    const int rowoff = offsets[g];
    const bf16_t* B = w2b + (size_t)g * DIM * HID;
    const size_t habase = (size_t)(rowoff + mbase);

    __shared__ bf16_t sA[128 * 64];
    __shared__ bf16_t sB[128 * 64];

    const int tid = threadIdx.x;
    const int wave = tid >> 6, lane = tid & 63;

    const bf16_t* pa[4]; const bf16_t* pb[4];
#pragma unroll
    for (int t = 0; t < 4; t++) {
        const int U = wave * 256 + t * 64 + lane;
        const int row = U >> 3;
        const int c = (U & 7) ^ ((row >> 1) & 7);
        pa[t] = Hin + (habase + row) * (size_t)HID + c * 8;
        pb[t] = B + (size_t)(nbase + row) * HID + c * 8;
    }

    const int wm = (wave >> 1) * 64, wn = (wave & 1) * 64;
    const int fm = lane & 15, fq = lane >> 4;
    const int swz = (fm >> 1) & 7;
    int aoff[4][2], boff[4][2];
#pragma unroll
    for (int i = 0; i < 4; i++)
#pragma unroll
        for (int s = 0; s < 2; s++) {
            aoff[i][s] = (wm + i * 16 + fm) * 64 + ((s * 4 + fq) ^ swz) * 8;
            boff[i][s] = (wn + i * 16 + fm) * 64 + ((s * 4 + fq) ^ swz) * 8;
        }

    const f32x4 zero = {0.f, 0.f, 0.f, 0.f};
    f32x4 acc[4][4];
#pragma unroll
    for (int i = 0; i < 4; i++)
#pragma unroll
        for (int j = 0; j < 4; j++) acc[i][j] = zero;

    for (int k0 = 0; k0 < HID; k0 += 64) {
#pragma unroll
        for (int t = 0; t < 4; t++) {
            const int lb = (wave * 256 + t * 64) * 8;
            GLDS(pa[t], &sA[lb]);
            GLDS(pb[t], &sB[lb]);
            pa[t] += 64; pb[t] += 64;
        }
        __syncthreads();
#pragma unroll
        for (int s = 0; s < 2; s++) {
            bf16x8 af[4], bbf[4];
#pragma unroll
            for (int i = 0; i < 4; i++) {
                af[i]  = *(const bf16x8*)&sA[aoff[i][s]];
                bbf[i] = *(const bf16x8*)&sB[boff[i][s]];
            }
#pragma unroll
            for (int i = 0; i < 4; i++)
#pragma unroll
                for (int j = 0; j < 4; j++)
                    acc[i][j] = __builtin_amdgcn_mfma_f32_16x16x32_bf16(af[i], bbf[j], acc[i][j], 0, 0, 0);
        }
        __syncthreads();
    }

#pragma unroll
    for (int i = 0; i < 4; i++) {
#pragma unroll
        for (int r = 0; r < 4; r++) {
            const int lr = wm + i * 16 + fq * 4 + r;
            if (mbase + lr < cnt) {
                float* yp = Y + (size_t)(rowoff + mbase + lr) * DIM + nbase + wn;
#pragma unroll
                for (int j = 0; j < 4; j++) yp[j * 16 + fm] = acc[i][j][r];
            }
        }
    }
}

// ---------------- combine: out[t] = w0*Y[r0] + w1*Y[r1] + Y[16384+t] ----------------
__global__ void combine_kernel(const float* __restrict__ Y, const int* __restrict__ tokrow,
                               const float* __restrict__ tkw, float* __restrict__ out)
{
    const int t = blockIdx.x;
    const int d = threadIdx.x;              // 256 threads, one float4 each
    const int r0 = tokrow[t * 2 + 0];
    const int r1 = tokrow[t * 2 + 1];
    const float w0 = tkw[t * 2 + 0];
    const float w1 = tkw[t * 2 + 1];
    const float4 a = ((const float4*)(Y + (size_t)r0 * DIM))[d];
    const float4 b = ((const float4*)(Y + (size_t)r1 * DIM))[d];
    const float4 c = ((const float4*)(Y + (size_t)(16384 + t) * DIM))[d];
    float4 o;
    o.x = w0 * a.x + w1 * b.x + c.x;
    o.y = w0 * a.y + w1 * b.y + c.y;
    o.z = w0 * a.z + w1 * b.z + c.z;
    o.w = w0 * a.w + w1 * b.w + c.w;
    ((float4*)(out + (size_t)t * DIM))[d] = o;
}

extern "C" void kernel_launch(void* const* d_in, const int* in_sizes, int n_in,
                              void* d_out, int out_size, void* d_ws, size_t ws_size,
                              hipStream_t stream)
{
    const float* x   = (const float*)d_in[0];
    const float* gw  = (const float*)d_in[1];
    const float* w1  = (const float*)d_in[2];
    const float* w2  = (const float*)d_in[3];
    const float* w3  = (const float*)d_in[4];
    const float* sw1 = (const float*)d_in[5];
    const float* sw2 = (const float*)d_in[6];
    const float* sw3 = (const float*)d_in[7];
    float* out = (float*)d_out;
    char* ws = (char*)d_ws;

    bf16_t* H    = (bf16_t*)(ws + H_OFF);
    int* counts  = (int*)(ws + CNT_OFF);
    int* fill    = (int*)(ws + FILL_OFF);
    int* offs    = (int*)(ws + OFFS_OFF);
    int* tki     = (int*)(ws + TOPKI_OFF);
    float* tkw   = (float*)(ws + TOPKW_OFF);
    int* rowmap  = (int*)(ws + ROWMAP_OFF);
    int* tokrow  = (int*)(ws + TOKROW_OFF);
    bf16_t* xb   = (bf16_t*)(ws + XB_OFF);
    bf16_t* w1b  = (bf16_t*)(ws + W1B_OFF);
    bf16_t* w3b  = (bf16_t*)(ws + W3B_OFF);
    bf16_t* w2b  = (bf16_t*)(ws + W2B_OFF);
    float* Y     = (float*)(ws + Y_OFF);   // overlays w1b/w3b (dead after gemm1)

    (void)in_sizes; (void)n_in; (void)out_size; (void)ws_size;

    hipMemsetAsync(ws + CNT_OFF, 0, 64, stream);  // counts + fill

    CvtArgs ca;
    ca.s[0] = x;   ca.d[0] = xb;                           ca.n8[0] = T_TOKENS * DIM / 8;
    ca.s[1] = w1;  ca.d[1] = w1b;                          ca.n8[1] = NE * HID * DIM / 8;
    ca.s[2] = sw1; ca.d[2] = w1b + (size_t)NE * HID * DIM; ca.n8[2] = HID * DIM / 8;
    ca.s[3] = w3;  ca.d[3] = w3b;                          ca.n8[3] = NE * HID * DIM / 8;
    ca.s[4] = sw3; ca.d[4] = w3b + (size_t)NE * HID * DIM; ca.n8[4] = HID * DIM / 8;
    ca.s[5] = w2;  ca.d[5] = w2b;                          ca.n8[5] = NE * DIM * HID / 8;
    ca.s[6] = sw2; ca.d[6] = w2b + (size_t)NE * DIM * HID; ca.n8[6] = DIM * HID / 8;
    convert_kernel<<<dim3(1024, 7), 256, 0, stream>>>(ca);

    gate_kernel<<<T_TOKENS / 4, 256, 0, stream>>>(x, gw, tki, tkw, counts);
    offsets_kernel<<<1, 64, 0, stream>>>(counts, offs);
    scatter_kernel<<<T_TOKENS / 256, 256, 0, stream>>>(tki, offs, fill, rowmap, tokrow);
    gemm1_kernel<<<dim3(HID / 128, 9 * 64), 256, 0, stream>>>(xb, w1b, w3b, offs, counts, rowmap, H);
    gemm2_kernel<<<dim3(DIM / 128, 9 * 64), 256, 0, stream>>>(H, w2b, offs, counts, Y);
    combine_kernel<<<T_TOKENS, 256, 0, stream>>>(Y, tokrow, tkw, out);
}